// Round 1
// 161.192 us; speedup vs baseline: 1.0211x; 1.0211x over previous
//
#include <hip/hip_runtime.h>

// GraphSAGE layer: B=8, N=5000, E=100000, D=128. All float tensors f32; edge_index int32.
// R18 pipeline (3 dispatches): memset(cnt) -> fill (XCD-affine buckets, u32-packed
//   entries {src:16|bf16(m):16}, 2 edges/thread + x->bf16 conv + packW)
//   -> fused (group-parallel bf16 gather -> MFMA gemm [x|agg]@[Ws;Wn] + ReLU+LN+mask).
// R17 post-mortem: fused_k 47.4us, MfmaUtil 2%, HBM 7.4%, VALUBusy 39% -> latency-bound.
// The node-serial gather (4 sequential gather_node_lds calls, each with 2 exposed L2
// round-trips + a 2-level shfl_xor reduce) was the critical path. R18: each 16-lane
// group owns ONE node (grp=lane>>4), each lane owns one 16B chunk (c8=lane&15); one
// flat masked loop over edge slots -> no cross-lane reduce, 8 loads in flight,
// metadata loads hoisted above xs staging.

#define B_ 8
#define N_ 5000
#define E_ 100000
#define D_ 128
#define EPS_ 1e-5f
#define NNODES (B_ * N_)   // 40000
#define NEDGES (B_ * E_)   // 800000
#define JB 313             // 16-node blocks per batch (312*16+8 = 5000)
#define PPB ((E_ / 2 + 255) / 256)    // 196 pair-blocks per batch (E even)
#define FILL_BLOCKS (8 * PPB)         // 1568
#define CONV_BLOCKS 2500              // x -> bf16: 2048 elems/block
#define CAP 64             // bucket capacity per node (avg deg 20, P(ovf) ~ 5e-14)
#define LDSP 136           // padded bf16 row stride (272 B -> 2-way bank alias, free)

typedef __bf16 bf16x8 __attribute__((ext_vector_type(8)));
typedef float  f32x4  __attribute__((ext_vector_type(4)));

static __device__ __forceinline__ unsigned short f2bf(float f) {
    union { float f; unsigned int i; } c; c.f = f;
    unsigned int i = c.i;
    i += 0x7fffu + ((i >> 16) & 1u);
    return (unsigned short)(i >> 16);
}
static __device__ __forceinline__ float bflo(unsigned int u) {
    return __uint_as_float(u << 16);
}
static __device__ __forceinline__ float bfhi(unsigned int u) {
    return __uint_as_float(u & 0xffff0000u);
}

// ---------- fill: XCD-affine u32 buckets (0..1567) + x->bf16 (..4067) + packW ----------
__global__ __launch_bounds__(256) void fill_k(
    const int* __restrict__ ei, const float* __restrict__ em,
    int* __restrict__ cnt, unsigned int* __restrict__ entries,
    const float* __restrict__ x, unsigned short* __restrict__ xbf,
    const float* __restrict__ Wself, const float* __restrict__ Wnb,
    unsigned short* __restrict__ Bt)
{
    int blk = blockIdx.x;
    if (blk < FILL_BLOCKS) {
        int b = blk & 7;                    // batch -> XCD (round-robin dispatch)
        int p = (blk >> 3) * 256 + threadIdx.x;
        if (p >= E_ / 2) return;
        int e = 2 * p;                      // pair e, e+1 (E even -> both valid)
        const int* eib = ei + (size_t)b * 2 * E_;
        int2   sv = *(const int2*)(eib + e);
        int2   tv = *(const int2*)(eib + E_ + e);
        float2 mv = *(const float2*)(em + (size_t)b * E_ + e);
        int gb = b * N_;
        if (mv.x != 0.0f) {
            int g = gb + tv.x;
            int slot = atomicAdd(&cnt[g], 1);
            if (slot < CAP)
                entries[((size_t)g << 6) + slot] =
                    (unsigned int)(gb + sv.x) | ((unsigned int)f2bf(mv.x) << 16);
        }
        if (mv.y != 0.0f) {
            int g = gb + tv.y;
            int slot = atomicAdd(&cnt[g], 1);
            if (slot < CAP)
                entries[((size_t)g << 6) + slot] =
                    (unsigned int)(gb + sv.y) | ((unsigned int)f2bf(mv.y) << 16);
        }
    } else if (blk < FILL_BLOCKS + CONV_BLOCKS) {
        size_t base = (size_t)(blk - FILL_BLOCKS) * 2048 + threadIdx.x * 8;
        float4 va = *(const float4*)(x + base);
        float4 vb = *(const float4*)(x + base + 4);
        uint4 o;
        o.x = (unsigned int)f2bf(va.x) | ((unsigned int)f2bf(va.y) << 16);
        o.y = (unsigned int)f2bf(va.z) | ((unsigned int)f2bf(va.w) << 16);
        o.z = (unsigned int)f2bf(vb.x) | ((unsigned int)f2bf(vb.y) << 16);
        o.w = (unsigned int)f2bf(vb.z) | ((unsigned int)f2bf(vb.w) << 16);
        *(uint4*)(xbf + base) = o;
    } else {
        int n = blk - FILL_BLOCKS - CONV_BLOCKS;   // 0..127
        int k = threadIdx.x;                       // 0..255
        float v = (k < 128) ? Wself[(size_t)k * D_ + n]
                            : Wnb[(size_t)(k - 128) * D_ + n];
        Bt[(size_t)n * 256 + k] = f2bf(v);
    }
}

// ---------- fused gather + MFMA GEMM + ReLU + LN + mask ----------
// Grid 8*JB; blk&7 = batch (XCD affinity), blk>>3 = 16-node group within batch.
__global__ __launch_bounds__(256) void fused_k(
    const unsigned short* __restrict__ xbf, const int* __restrict__ cnt,
    const unsigned int* __restrict__ entries,
    const unsigned short* __restrict__ Bt,
    const float* __restrict__ bself, const float* __restrict__ bnb,
    const float* __restrict__ gamma, const float* __restrict__ beta,
    const float* __restrict__ nmask, float* __restrict__ out)
{
    __shared__ unsigned short xs[16][LDSP];
    __shared__ unsigned short as[16][LDSP];
    __shared__ float red[4][2][16];

    int t = threadIdx.x;
    int lane = t & 63, wv = t >> 6;
    int b = blockIdx.x & 7;
    int j = blockIdx.x >> 3;               // 0..JB-1
    int i0 = j * 16;
    int g0 = b * N_ + i0;
    int limit = N_ - i0; if (limit > 16) limit = 16;

    int grp = lane >> 4;                   // lane-group: which of the wave's 4 nodes
    int c8  = lane & 15;                   // 16B chunk (8 bf16) within the 256B row
    int myrow = (wv << 2) + grp;           // 0..15: node row owned by this lane-group

    // Issue gather metadata loads first; latency hides under xs staging.
    int ga = g0 + ((myrow < limit) ? myrow : 0);      // clamped (cnt has no padding)
    int dgr = cnt[ga];
    unsigned int ee = entries[((size_t)ga << 6) + c8]; // slots 0..15, lane c8 holds slot c8

    // Phase A1: stage own xbf rows into LDS (4 rows/wave).
    #pragma unroll
    for (int lr = wv * 4; lr < wv * 4 + 4; ++lr) {
        unsigned int v = 0;
        if (lr < limit)
            v = ((const unsigned int*)(xbf + (size_t)(g0 + lr) * D_))[lane];
        ((unsigned int*)&xs[lr][0])[lane] = v;
    }

    // Phase A2: group-parallel gather. Group g accumulates its node's masked
    // neighbor sum in registers: lane (g,c8) holds elements 8*c8..8*c8+7.
    int dgg = (myrow < limit) ? ((dgr > CAP) ? CAP : dgr) : 0;

    float a[8];
    #pragma unroll
    for (int i = 0; i < 8; ++i) a[i] = 0.f;
    float cs = 0.f;

    for (int k0 = 0; ; k0 += 16) {
        unsigned int een = 0u;
        if (k0 + 16 < CAP)                  // prefetch next slot chunk
            een = entries[((size_t)ga << 6) + (k0 + 16) + c8];
        #pragma unroll 8
        for (int k = 0; k < 16; ++k) {
            unsigned int ej = (unsigned int)__shfl((int)ee, (lane & 48) + k, 64);
            int   ok = (k0 + k) < dgg;
            int   sj = ok ? (int)(ej & 0xffffu) : 0;              // masked -> row 0
            float mj = ok ? __uint_as_float(ej & 0xffff0000u) : 0.0f;
            uint4 v = *(const uint4*)(xbf + (size_t)sj * D_ + (c8 << 3));
            a[0] += bflo(v.x) * mj; a[1] += bfhi(v.x) * mj;
            a[2] += bflo(v.y) * mj; a[3] += bfhi(v.y) * mj;
            a[4] += bflo(v.z) * mj; a[5] += bfhi(v.z) * mj;
            a[6] += bflo(v.w) * mj; a[7] += bfhi(v.w) * mj;
            cs += mj;
        }
        if (k0 + 16 >= CAP) break;
        if (__all(dgg <= k0 + 16)) break;   // all 4 nodes of this wave done
        ee = een;
    }

    // cs is uniform within the group (every lane summed every edge's m).
    {
        float inv = 1.0f / fmaxf(cs, 1.0f);
        uint4 o;
        o.x = (unsigned int)f2bf(a[0] * inv) | ((unsigned int)f2bf(a[1] * inv) << 16);
        o.y = (unsigned int)f2bf(a[2] * inv) | ((unsigned int)f2bf(a[3] * inv) << 16);
        o.z = (unsigned int)f2bf(a[4] * inv) | ((unsigned int)f2bf(a[5] * inv) << 16);
        o.w = (unsigned int)f2bf(a[6] * inv) | ((unsigned int)f2bf(a[7] * inv) << 16);
        *(uint4*)&as[myrow][c8 << 3] = o;   // rows >= limit: dgg=0 -> zeros
    }
    __syncthreads();

    // Phase B: wave wv owns col-tiles 2wv, 2wv+1.
    int quad = lane >> 4;
    int lcol = lane & 15;

    f32x4 acc[2];
    acc[0] = (f32x4)0.0f;
    acc[1] = (f32x4)0.0f;

    #pragma unroll
    for (int kk = 0; kk < 4; ++kk) {
        int kof = kk * 32 + quad * 8;
        bf16x8 av = *(const bf16x8*)&xs[lcol][kof];
        #pragma unroll
        for (int p = 0; p < 2; ++p) {
            int tt = wv * 2 + p;
            bf16x8 bf = *(const bf16x8*)(Bt + (size_t)(tt * 16 + lcol) * 256 + kof);
            acc[p] = __builtin_amdgcn_mfma_f32_16x16x32_bf16(av, bf, acc[p], 0, 0, 0);
        }
    }
    #pragma unroll
    for (int kk = 0; kk < 4; ++kk) {
        int kof = kk * 32 + quad * 8;
        bf16x8 av = *(const bf16x8*)&as[lcol][kof];
        #pragma unroll
        for (int p = 0; p < 2; ++p) {
            int tt = wv * 2 + p;
            bf16x8 bf = *(const bf16x8*)(Bt + (size_t)(tt * 16 + lcol) * 256 + 128 + kof);
            acc[p] = __builtin_amdgcn_mfma_f32_16x16x32_bf16(av, bf, acc[p], 0, 0, 0);
        }
    }

    // bias + ReLU; per-wave 32-col LN partials
    float h[2][4];
    float s[4] = {0, 0, 0, 0}, q[4] = {0, 0, 0, 0};
    float gam[2], bet[2];
    #pragma unroll
    for (int p = 0; p < 2; ++p) {
        int col = (wv * 2 + p) * 16 + lcol;
        float bs = bself[col] + bnb[col];
        gam[p] = gamma[col];
        bet[p] = beta[col];
        #pragma unroll
        for (int r = 0; r < 4; ++r) {
            float v = fmaxf(acc[p][r] + bs, 0.0f);
            h[p][r] = v;
            s[r] += v;
            q[r] += v * v;
        }
    }
    #pragma unroll
    for (int r = 0; r < 4; ++r) {
        #pragma unroll
        for (int off = 1; off <= 8; off <<= 1) {
            s[r] += __shfl_xor(s[r], off, 64);
            q[r] += __shfl_xor(q[r], off, 64);
        }
    }
    if (lcol == 0) {
        #pragma unroll
        for (int r = 0; r < 4; ++r) {
            red[wv][0][quad * 4 + r] = s[r];
            red[wv][1][quad * 4 + r] = q[r];
        }
    }
    __syncthreads();

    #pragma unroll
    for (int r = 0; r < 4; ++r) {
        int row = quad * 4 + r;
        int irow = i0 + row;
        if (irow >= N_) continue;
        float S = red[0][0][row] + red[1][0][row] + red[2][0][row] + red[3][0][row];
        float Q = red[0][1][row] + red[1][1][row] + red[2][1][row] + red[3][1][row];
        float mu = S * (1.0f / D_);
        float var = Q * (1.0f / D_) - mu * mu;
        float rin = rsqrtf(fmaxf(var, 0.0f) + EPS_);
        int g = b * N_ + irow;
        float mk = nmask[g];
        float* op = out + (size_t)g * D_;
        #pragma unroll
        for (int p = 0; p < 2; ++p) {
            int col = (wv * 2 + p) * 16 + lcol;
            op[col] = ((h[p][r] - mu) * rin * gam[p] + bet[p]) * mk;
        }
    }
}

extern "C" void kernel_launch(void* const* d_in, const int* in_sizes, int n_in,
                              void* d_out, int out_size, void* d_ws, size_t ws_size,
                              hipStream_t stream)
{
    const float* x     = (const float*)d_in[0];
    const int*   ei    = (const int*)d_in[1];
    const float* nmask = (const float*)d_in[2];
    const float* em    = (const float*)d_in[3];
    const float* Wself = (const float*)d_in[4];
    const float* bself = (const float*)d_in[5];
    const float* Wnb   = (const float*)d_in[6];
    const float* bnb   = (const float*)d_in[7];
    const float* gamma = (const float*)d_in[8];
    const float* beta  = (const float*)d_in[9];
    float* out = (float*)d_out;

    // ws: cnt int[40000] | entries u32[40000*64] (10.24 MB) | Bt bf16[128*256]
    //     | xbf bf16[40000*128] (10.24 MB)   -> ~21 MB total
    int* cnt = (int*)d_ws;
    unsigned int* entries = (unsigned int*)(cnt + NNODES);       // byte 160000, 4-al
    unsigned short* Bt = (unsigned short*)(entries + (size_t)NNODES * CAP);
    unsigned short* xbf = Bt + (size_t)128 * 256;                // 16-aligned

    hipMemsetAsync(cnt, 0, NNODES * sizeof(int), stream);
    fill_k<<<FILL_BLOCKS + CONV_BLOCKS + 128, 256, 0, stream>>>(
        ei, em, cnt, entries, x, xbf, Wself, Wnb, Bt);
    fused_k<<<8 * JB, 256, 0, stream>>>(xbf, cnt, entries, Bt,
                                        bself, bnb, gamma, beta, nmask, out);
}